// Round 3
// baseline (85.078 us; speedup 1.0000x reference)
//
#include <hip/hip_runtime.h>
#include <hip/hip_bf16.h>

// Glow coupling layer, fused. rows N = 262144, C = 64.
// r2 = MLP_s2(x2); y1 = e(s2)*x1 + t2; r1 = MLP_s1(y1); y2 = e(s1)*x2 + t1.
//
// Round 3: MFMA operand swap (W as A, activations as B) -> D[f][r] layout:
// lane reg i = 4 consecutive f-columns => packed cvt_pk + ds_write_b64
// epilogues, b128 s-stash, dwordx4 output stores. Custom e(s) =
// exp2(K*atan(0.2 s)) polynomial. Bias preloaded into MFMA accumulator.
//
// Frag maps (m89/m91 verified):
//   A frag: lane l holds A[row=l&15][k=(l>>4)*8+j]
//   B frag: lane l holds B[k=(l>>4)*8+j][col=l&15]   (same per-lane map!)
//   C/D  : lane l reg i -> (row=(l>>4)*4+i, col=l&15)

using bf16x8 = __attribute__((ext_vector_type(8))) short;
using f32x4  = __attribute__((ext_vector_type(4))) float;
using u32x2  = __attribute__((ext_vector_type(2))) unsigned int;

__device__ __forceinline__ unsigned short f2bf(float f) {
    unsigned int u = __float_as_uint(f);
    u += 0x7FFFu + ((u >> 16) & 1u);
    return (unsigned short)(u >> 16);
}
__device__ __forceinline__ unsigned int pk2bf(float a, float b) {
    union { __hip_bfloat162 h; unsigned int u; } cv;
    cv.h = __float22bfloat162_rn(float2{a, b});
    return cv.u;   // low16 = bf16(a), high16 = bf16(b)
}
__device__ __forceinline__ f32x4 mfma16(bf16x8 a, bf16x8 b, f32x4 c) {
    return __builtin_amdgcn_mfma_f32_16x16x32_bf16(a, b, c, 0, 0, 0);
}

// e(s) = exp(3.18*atan(s/5)) = exp2(4.5877702*atan(0.2 s)).
// atan minimax deg-11 (err ~1e-5), coeffs pre-scaled by K = 4.5877702.
__device__ __forceinline__ float e_fun(float s) {
    float z = 0.2f * s;
    float a = fabsf(z);
    float t = fminf(a, __builtin_amdgcn_rcpf(a));   // a<=1 ? a : 1/a
    float u = t * t;
    float p = -0.0537741f;
    p = fmaf(p, u,  0.2415614f);
    p = fmaf(p, u, -0.5341673f);
    p = fmaf(p, u,  0.8879339f);
    p = fmaf(p, u, -1.5260000f);
    p = fmaf(p, u,  4.5876659f);
    p = p * t;
    float r = (a > 1.0f) ? (7.2064613f - p) : p;    // K*pi/2 - p
    r = copysignf(r, s);
    return __builtin_amdgcn_exp2f(r);
}

#define X1P 36    // f32 pitch (16B-aligned rows)
#define APP 40    // bf16 pitch, plane arrays
#define HP  136   // bf16 pitch, h buffers
#define SP  36    // f32 pitch, sbuf

#define OFF_X1   0        // f32  [64][36]  = 9216
#define OFF_AHI2 9216     // bf16 [64][40]  = 5120
#define OFF_ALO2 14336    // bf16 [64][40]  = 5120
#define OFF_H1   19456    // bf16 [64][136] = 17408  (sbuf f32[64][36] aliases)
#define OFF_H2   36864    // bf16 [64][136] = 17408  (ahi1/alo1 alias)
#define LDS_BYTES 54272   // x3 = 162816 <= 163840 -> 3 blocks/CU

#define BIAS_OFF 114688           // 112 tiles * 1024B
#define WS_NEED  (114688 + 2560)

struct MlpW {
    bf16x8 wb1[2];
    bf16x8 wb2[2][4];
    bf16x8 wb3[4];
    f32x4  b1v[2], b2v[2], b3v;
};

// ---- fallback (MODE 0): convert weights per block ----
__device__ __forceinline__ bf16x8 load_wfrag(const float* __restrict__ W, int K, int frow, int k0) {
    const float4* p = reinterpret_cast<const float4*>(W + (size_t)frow * K + k0);
    float4 a = p[0], b = p[1];
    bf16x8 r;
    r[0] = (short)f2bf(a.x); r[1] = (short)f2bf(a.y);
    r[2] = (short)f2bf(a.z); r[3] = (short)f2bf(a.w);
    r[4] = (short)f2bf(b.x); r[5] = (short)f2bf(b.y);
    r[6] = (short)f2bf(b.z); r[7] = (short)f2bf(b.w);
    return r;
}
__device__ __forceinline__ void load_w_convert(
    const float* __restrict__ w1, const float* __restrict__ b1,
    const float* __restrict__ w2, const float* __restrict__ b2,
    const float* __restrict__ w3, const float* __restrict__ b3,
    int wave, int lane, MlpW& W)
{
    const int lr = lane & 15, lg = lane >> 4;
    #pragma unroll
    for (int f = 0; f < 2; ++f) {
        int ft = 2 * wave + f;
        W.wb1[f] = load_wfrag(w1, 32, 16 * ft + lr, lg * 8);
        W.b1v[f] = *reinterpret_cast<const f32x4*>(b1 + 16 * ft + 4 * lg);
        W.b2v[f] = *reinterpret_cast<const f32x4*>(b2 + 16 * ft + 4 * lg);
        #pragma unroll
        for (int ks = 0; ks < 4; ++ks)
            W.wb2[f][ks] = load_wfrag(w2, 128, 16 * ft + lr, 32 * ks + lg * 8);
    }
    #pragma unroll
    for (int ks = 0; ks < 4; ++ks)
        W.wb3[ks] = load_wfrag(w3, 128, 16 * wave + lr, 32 * ks + lg * 8);
    W.b3v = *reinterpret_cast<const f32x4*>(b3 + 16 * wave + 4 * lg);
}

// ---- prepped (MODE 1): straight uint4 loads from d_ws ----
__device__ __forceinline__ void load_w_prepped(const char* __restrict__ wsb,
                                               int mlp, int wave, int lane, MlpW& W)
{
    const int lg = lane >> 4;
    const uint4* base = reinterpret_cast<const uint4*>(wsb);
    union U { uint4 q; bf16x8 v; };
    #pragma unroll
    for (int f = 0; f < 2; ++f) {
        U u; u.q = base[(mlp * 56 + 2 * wave + f) * 64 + lane];
        W.wb1[f] = u.v;
        #pragma unroll
        for (int ks = 0; ks < 4; ++ks) {
            U u2; u2.q = base[(mlp * 56 + 8 + (2 * wave + f) * 4 + ks) * 64 + lane];
            W.wb2[f][ks] = u2.v;
        }
    }
    #pragma unroll
    for (int ks = 0; ks < 4; ++ks) {
        U u3; u3.q = base[(mlp * 56 + 40 + wave * 4 + ks) * 64 + lane];
        W.wb3[ks] = u3.v;
    }
    const float* bias = reinterpret_cast<const float*>(wsb + BIAS_OFF) + mlp * 320;
    #pragma unroll
    for (int f = 0; f < 2; ++f) {
        W.b1v[f] = *reinterpret_cast<const f32x4*>(bias + 16 * (2 * wave + f) + 4 * lg);
        W.b2v[f] = *reinterpret_cast<const f32x4*>(bias + 128 + 16 * (2 * wave + f) + 4 * lg);
    }
    W.b3v = *reinterpret_cast<const f32x4*>(bias + 256 + 16 * wave + 4 * lg);
}

// ---- 3-layer MLP, swapped operands: D[f][r] ----
// rr[m][i] = r[f = 16*wave + 4*lg + i][row = 16*m + lr]
__device__ __forceinline__ void run_mlp(const MlpW& W,
    const unsigned short* __restrict__ ahi, const unsigned short* __restrict__ alo,
    unsigned short* __restrict__ h1, unsigned short* __restrict__ h2,
    int wave, int lane, f32x4 (&rr)[4])
{
    const int lr = lane & 15, lg = lane >> 4;

    // layer 1: K=32, hi+lo planes
    #pragma unroll
    for (int m = 0; m < 4; ++m) {
        const int r = 16 * m + lr;
        bf16x8 ah = *reinterpret_cast<const bf16x8*>(ahi + r * APP + lg * 8);
        bf16x8 al = *reinterpret_cast<const bf16x8*>(alo + r * APP + lg * 8);
        #pragma unroll
        for (int f = 0; f < 2; ++f) {
            f32x4 acc = W.b1v[f];
            acc = mfma16(W.wb1[f], ah, acc);
            acc = mfma16(W.wb1[f], al, acc);
            unsigned int p0 = pk2bf(fmaxf(acc[0], 0.f), fmaxf(acc[1], 0.f));
            unsigned int p1 = pk2bf(fmaxf(acc[2], 0.f), fmaxf(acc[3], 0.f));
            *reinterpret_cast<u32x2*>(h1 + r * HP + 16 * (2 * wave + f) + 4 * lg) = u32x2{p0, p1};
        }
    }
    __syncthreads();

    // layer 2: K=128
    #pragma unroll
    for (int m = 0; m < 4; ++m) {
        const int r = 16 * m + lr;
        bf16x8 hf[4];
        #pragma unroll
        for (int ks = 0; ks < 4; ++ks)
            hf[ks] = *reinterpret_cast<const bf16x8*>(h1 + r * HP + 32 * ks + lg * 8);
        #pragma unroll
        for (int f = 0; f < 2; ++f) {
            f32x4 acc = W.b2v[f];
            #pragma unroll
            for (int ks = 0; ks < 4; ++ks)
                acc = mfma16(W.wb2[f][ks], hf[ks], acc);
            unsigned int p0 = pk2bf(fmaxf(acc[0], 0.f), fmaxf(acc[1], 0.f));
            unsigned int p1 = pk2bf(fmaxf(acc[2], 0.f), fmaxf(acc[3], 0.f));
            *reinterpret_cast<u32x2*>(h2 + r * HP + 16 * (2 * wave + f) + 4 * lg) = u32x2{p0, p1};
        }
    }
    __syncthreads();

    // layer 3: K=128, wave owns f-rows 16w..16w+15
    #pragma unroll
    for (int m = 0; m < 4; ++m) {
        const int r = 16 * m + lr;
        f32x4 acc = W.b3v;
        #pragma unroll
        for (int ks = 0; ks < 4; ++ks) {
            bf16x8 hf = *reinterpret_cast<const bf16x8*>(h2 + r * HP + 32 * ks + lg * 8);
            acc = mfma16(W.wb3[ks], hf, acc);
        }
        rr[m] = acc;
    }
}

// ---- weight prep ----
extern "C" __global__ void __launch_bounds__(256)
glow_prep(const float* __restrict__ s2w1, const float* __restrict__ s2w2,
          const float* __restrict__ s2w3, const float* __restrict__ s1w1,
          const float* __restrict__ s1w2, const float* __restrict__ s1w3,
          const float* __restrict__ s2b1, const float* __restrict__ s2b2,
          const float* __restrict__ s2b3, const float* __restrict__ s1b1,
          const float* __restrict__ s1b2, const float* __restrict__ s1b3,
          char* __restrict__ wsb)
{
    const int wave = threadIdx.x >> 6, lane = threadIdx.x & 63;
    const int lr = lane & 15, lg = lane >> 4;
    const int gw = blockIdx.x * 4 + wave;

    if (gw < 112) {
        int mlp = gw / 56, t = gw % 56;
        const float* Ws[2][3] = {{s2w1, s2w2, s2w3}, {s1w1, s1w2, s1w3}};
        const float* W; int K, row, k0;
        if (t < 8)       { W = Ws[mlp][0]; K = 32;  row = 16 * t + lr;          k0 = lg * 8; }
        else if (t < 40) { int u = t - 8;  W = Ws[mlp][1]; K = 128; row = 16 * (u >> 2) + lr; k0 = 32 * (u & 3) + lg * 8; }
        else             { int u = t - 40; W = Ws[mlp][2]; K = 128; row = 16 * (u >> 2) + lr; k0 = 32 * (u & 3) + lg * 8; }
        const float* p = W + (size_t)row * K + k0;
        union U { uint4 q; bf16x8 v; } u;
        #pragma unroll
        for (int j = 0; j < 8; ++j) u.v[j] = (short)f2bf(p[j]);
        reinterpret_cast<uint4*>(wsb)[gw * 64 + lane] = u.q;
    } else if (blockIdx.x == 28) {
        const float* Bs[6] = {s2b1, s2b2, s2b3, s1b1, s1b2, s1b3};
        const int sz[6] = {128, 128, 64, 128, 128, 64};
        float* dst = reinterpret_cast<float*>(wsb + BIAS_OFF);
        for (int i = threadIdx.x; i < 640; i += 256) {
            int j = i, a = 0;
            while (j >= sz[a]) { j -= sz[a]; ++a; }
            dst[i] = Bs[a][j];
        }
    }
}

template<int MODE>
__global__ void __launch_bounds__(256, 3)
glow_main(const float* __restrict__ x,
          const float* __restrict__ s1w1, const float* __restrict__ s1b1,
          const float* __restrict__ s1w2, const float* __restrict__ s1b2,
          const float* __restrict__ s1w3, const float* __restrict__ s1b3,
          const float* __restrict__ s2w1, const float* __restrict__ s2b1,
          const float* __restrict__ s2w2, const float* __restrict__ s2b2,
          const float* __restrict__ s2w3, const float* __restrict__ s2b3,
          const char* __restrict__ wsb, float* __restrict__ out)
{
    __shared__ __align__(16) char lds[LDS_BYTES];
    float*          x1   = reinterpret_cast<float*>(lds + OFF_X1);
    unsigned short* ahi2 = reinterpret_cast<unsigned short*>(lds + OFF_AHI2);
    unsigned short* alo2 = reinterpret_cast<unsigned short*>(lds + OFF_ALO2);
    unsigned short* h1   = reinterpret_cast<unsigned short*>(lds + OFF_H1);
    unsigned short* h2   = reinterpret_cast<unsigned short*>(lds + OFF_H2);
    float*          sbuf = reinterpret_cast<float*>(lds + OFF_H1);          // alias h1
    unsigned short* ahi1 = reinterpret_cast<unsigned short*>(lds + OFF_H2); // alias h2
    unsigned short* alo1 = reinterpret_cast<unsigned short*>(lds + OFF_H2 + 5120);

    const int tid  = threadIdx.x;
    const int wave = tid >> 6, lane = tid & 63;
    const int lr = lane & 15, lg = lane >> 4;
    const size_t rowbase = (size_t)blockIdx.x * 64;
    const float* xblk = x + rowbase * 64;

    // ---- Phase A: stage x1 (f32) and x2 (hi/lo bf16 planes) ----
    #pragma unroll
    for (int it = 0; it < 4; ++it) {
        int idx = (it * 256 + tid) * 4;
        int r = idx >> 6, c = idx & 63;
        f32x4 v = *reinterpret_cast<const f32x4*>(xblk + idx);
        if (c < 32) {
            *reinterpret_cast<f32x4*>(x1 + r * X1P + c) = v;
        } else {
            int cc = c - 32;
            unsigned int h0 = pk2bf(v[0], v[1]);
            unsigned int h1p = pk2bf(v[2], v[3]);
            float f0 = __uint_as_float(h0 << 16);
            float f1 = __uint_as_float(h0 & 0xFFFF0000u);
            float f2 = __uint_as_float(h1p << 16);
            float f3 = __uint_as_float(h1p & 0xFFFF0000u);
            unsigned int l0 = pk2bf(v[0] - f0, v[1] - f1);
            unsigned int l1 = pk2bf(v[2] - f2, v[3] - f3);
            *reinterpret_cast<u32x2*>(ahi2 + r * APP + cc) = u32x2{h0, h1p};
            *reinterpret_cast<u32x2*>(alo2 + r * APP + cc) = u32x2{l0, l1};
        }
    }

    MlpW W;
    if (MODE) load_w_prepped(wsb, 0, wave, lane, W);
    else      load_w_convert(s2w1, s2b1, s2w2, s2b2, s2w3, s2b3, wave, lane, W);
    __syncthreads();

    f32x4 rr[4];

    // ---- MLP s2 on x2 ----
    run_mlp(W, ahi2, alo2, h1, h2, wave, lane, rr);

    // prefetch s1 weights (independent of LDS phases below)
    if (MODE) load_w_prepped(wsb, 1, wave, lane, W);
    else      load_w_convert(s1w1, s1b1, s1w2, s1b2, s1w3, s1b3, wave, lane, W);

    // epilogue 1: stash s2 (waves 0,1: f=0..31) -> exp all threads -> combine (waves 2,3)
    if (wave < 2) {
        #pragma unroll
        for (int m = 0; m < 4; ++m)
            *reinterpret_cast<f32x4*>(sbuf + (16 * m + lr) * SP + 16 * wave + 4 * lg) = rr[m];
    }
    __syncthreads();
    {
        int r = tid >> 2, c0 = (tid & 3) * 8;
        float* p = sbuf + r * SP + c0;
        f32x4 a = *reinterpret_cast<f32x4*>(p);
        f32x4 b = *reinterpret_cast<f32x4*>(p + 4);
        #pragma unroll
        for (int j = 0; j < 4; ++j) { a[j] = e_fun(a[j]); b[j] = e_fun(b[j]); }
        *reinterpret_cast<f32x4*>(p) = a;
        *reinterpret_cast<f32x4*>(p + 4) = b;
    }
    __syncthreads();
    if (wave >= 2) {
        const int c = 16 * (wave - 2) + 4 * lg;    // 0..31, 4 consecutive
        #pragma unroll
        for (int m = 0; m < 4; ++m) {
            const int r = 16 * m + lr;
            f32x4 e4 = *reinterpret_cast<const f32x4*>(sbuf + r * SP + c);
            f32x4 x4 = *reinterpret_cast<const f32x4*>(x1 + r * X1P + c);
            f32x4 y;
            #pragma unroll
            for (int i = 0; i < 4; ++i) y[i] = fmaf(e4[i], x4[i], rr[m][i]);
            *reinterpret_cast<f32x4*>(out + (rowbase + r) * 64 + c) = y;
            unsigned int h0 = pk2bf(y[0], y[1]);
            unsigned int h1p = pk2bf(y[2], y[3]);
            float f0 = __uint_as_float(h0 << 16);
            float f1 = __uint_as_float(h0 & 0xFFFF0000u);
            float f2 = __uint_as_float(h1p << 16);
            float f3 = __uint_as_float(h1p & 0xFFFF0000u);
            unsigned int l0 = pk2bf(y[0] - f0, y[1] - f1);
            unsigned int l1 = pk2bf(y[2] - f2, y[3] - f3);
            *reinterpret_cast<u32x2*>(ahi1 + r * APP + c) = u32x2{h0, h1p};
            *reinterpret_cast<u32x2*>(alo1 + r * APP + c) = u32x2{l0, l1};
        }
    }
    __syncthreads();

    // ---- MLP s1 on y1 ----
    run_mlp(W, ahi1, alo1, h1, h2, wave, lane, rr);

    // epilogue 2: stash s1 -> exp -> y2 = e(s1)*x2 + t1
    if (wave < 2) {
        #pragma unroll
        for (int m = 0; m < 4; ++m)
            *reinterpret_cast<f32x4*>(sbuf + (16 * m + lr) * SP + 16 * wave + 4 * lg) = rr[m];
    }
    __syncthreads();
    {
        int r = tid >> 2, c0 = (tid & 3) * 8;
        float* p = sbuf + r * SP + c0;
        f32x4 a = *reinterpret_cast<f32x4*>(p);
        f32x4 b = *reinterpret_cast<f32x4*>(p + 4);
        #pragma unroll
        for (int j = 0; j < 4; ++j) { a[j] = e_fun(a[j]); b[j] = e_fun(b[j]); }
        *reinterpret_cast<f32x4*>(p) = a;
        *reinterpret_cast<f32x4*>(p + 4) = b;
    }
    __syncthreads();
    if (wave >= 2) {
        const int c = 16 * (wave - 2) + 4 * lg;
        #pragma unroll
        for (int m = 0; m < 4; ++m) {
            const int r = 16 * m + lr;
            f32x4 e4 = *reinterpret_cast<const f32x4*>(sbuf + r * SP + c);
            u32x2 uh = *reinterpret_cast<const u32x2*>(ahi2 + r * APP + c);
            u32x2 ul = *reinterpret_cast<const u32x2*>(alo2 + r * APP + c);
            f32x4 x2v;
            x2v[0] = __uint_as_float(uh[0] << 16)          + __uint_as_float(ul[0] << 16);
            x2v[1] = __uint_as_float(uh[0] & 0xFFFF0000u)  + __uint_as_float(ul[0] & 0xFFFF0000u);
            x2v[2] = __uint_as_float(uh[1] << 16)          + __uint_as_float(ul[1] << 16);
            x2v[3] = __uint_as_float(uh[1] & 0xFFFF0000u)  + __uint_as_float(ul[1] & 0xFFFF0000u);
            f32x4 y;
            #pragma unroll
            for (int i = 0; i < 4; ++i) y[i] = fmaf(e4[i], x2v[i], rr[m][i]);
            *reinterpret_cast<f32x4*>(out + (rowbase + r) * 64 + 32 + c) = y;
        }
    }
}

extern "C" void kernel_launch(void* const* d_in, const int* in_sizes, int n_in,
                              void* d_out, int out_size, void* d_ws, size_t ws_size,
                              hipStream_t stream) {
    const float* x    = (const float*)d_in[0];
    const float* s1w1 = (const float*)d_in[1];
    const float* s1b1 = (const float*)d_in[2];
    const float* s1w2 = (const float*)d_in[3];
    const float* s1b2 = (const float*)d_in[4];
    const float* s1w3 = (const float*)d_in[5];
    const float* s1b3 = (const float*)d_in[6];
    const float* s2w1 = (const float*)d_in[7];
    const float* s2b1 = (const float*)d_in[8];
    const float* s2w2 = (const float*)d_in[9];
    const float* s2b2 = (const float*)d_in[10];
    const float* s2w3 = (const float*)d_in[11];
    const float* s2b3 = (const float*)d_in[12];
    float* out = (float*)d_out;
    char* wsb  = (char*)d_ws;

    int nrows   = in_sizes[0] / 64;   // 262144
    int nblocks = nrows / 64;         // 4096

    if (ws_size >= (size_t)WS_NEED) {
        hipLaunchKernelGGL(glow_prep, dim3(29), dim3(256), 0, stream,
                           s2w1, s2w2, s2w3, s1w1, s1w2, s1w3,
                           s2b1, s2b2, s2b3, s1b1, s1b2, s1b3, wsb);
        hipLaunchKernelGGL((glow_main<1>), dim3(nblocks), dim3(256), 0, stream,
                           x, s1w1, s1b1, s1w2, s1b2, s1w3, s1b3,
                           s2w1, s2b1, s2w2, s2b2, s2w3, s2b3, wsb, out);
    } else {
        hipLaunchKernelGGL((glow_main<0>), dim3(nblocks), dim3(256), 0, stream,
                           x, s1w1, s1b1, s1w2, s1b2, s1w3, s1b3,
                           s2w1, s2b1, s2w2, s2b2, s2w3, s2b3, wsb, out);
    }
}